// Round 9
// baseline (138.635 us; speedup 1.0000x reference)
//
#include <hip/hip_runtime.h>

// Problem constants
#define B_DIM 128
#define T_DIM 2048
#define D_DIM 512
#define H_DIM 8
#define HD_DIM 64
#define CH 4                          // chunks (blocks) per batch row
#define ROWS_PER_BLOCK (T_DIM / CH)   // 512
#define WAVES 8                       // 512-thread blocks
#define ROWS_PER_WAVE (ROWS_PER_BLOCK / WAVES) // 64 == wave size (ballot)

typedef float f4v __attribute__((ext_vector_type(4)));

// ---------------------------------------------------------------------------
// Per-row body (identical math to round-5/8): 8-head dot partials ->
// reduce-scatter to head pair {hA, hA+4} -> dual-head online softmax with
// deferred max -> depth-2 prefetch reissue.
// ---------------------------------------------------------------------------
#define ROW_BODY(ROW, B0, B1)                                                  \
  {                                                                            \
    const int row_ = (ROW);                                                    \
    float p0 = B0.x * w[0];                                                    \
    float p1 = B0.x * w[1];                                                    \
    float p2 = B0.x * w[2];                                                    \
    float p3 = B0.x * w[3];                                                    \
    float p4 = B0.x * w[4];                                                    \
    float p5 = B0.x * w[5];                                                    \
    float p6 = B0.x * w[6];                                                    \
    float p7 = B0.x * w[7];                                                    \
    p0 = fmaf(B0.y, w[8+0], p0);  p1 = fmaf(B0.y, w[8+1], p1);                 \
    p2 = fmaf(B0.y, w[8+2], p2);  p3 = fmaf(B0.y, w[8+3], p3);                 \
    p4 = fmaf(B0.y, w[8+4], p4);  p5 = fmaf(B0.y, w[8+5], p5);                 \
    p6 = fmaf(B0.y, w[8+6], p6);  p7 = fmaf(B0.y, w[8+7], p7);                 \
    p0 = fmaf(B0.z, w[16+0], p0); p1 = fmaf(B0.z, w[16+1], p1);                \
    p2 = fmaf(B0.z, w[16+2], p2); p3 = fmaf(B0.z, w[16+3], p3);                \
    p4 = fmaf(B0.z, w[16+4], p4); p5 = fmaf(B0.z, w[16+5], p5);                \
    p6 = fmaf(B0.z, w[16+6], p6); p7 = fmaf(B0.z, w[16+7], p7);                \
    p0 = fmaf(B0.w, w[24+0], p0); p1 = fmaf(B0.w, w[24+1], p1);                \
    p2 = fmaf(B0.w, w[24+2], p2); p3 = fmaf(B0.w, w[24+3], p3);                \
    p4 = fmaf(B0.w, w[24+4], p4); p5 = fmaf(B0.w, w[24+5], p5);                \
    p6 = fmaf(B0.w, w[24+6], p6); p7 = fmaf(B0.w, w[24+7], p7);                \
    p0 = fmaf(B1.x, w[32+0], p0); p1 = fmaf(B1.x, w[32+1], p1);                \
    p2 = fmaf(B1.x, w[32+2], p2); p3 = fmaf(B1.x, w[32+3], p3);                \
    p4 = fmaf(B1.x, w[32+4], p4); p5 = fmaf(B1.x, w[32+5], p5);                \
    p6 = fmaf(B1.x, w[32+6], p6); p7 = fmaf(B1.x, w[32+7], p7);                \
    p0 = fmaf(B1.y, w[40+0], p0); p1 = fmaf(B1.y, w[40+1], p1);                \
    p2 = fmaf(B1.y, w[40+2], p2); p3 = fmaf(B1.y, w[40+3], p3);                \
    p4 = fmaf(B1.y, w[40+4], p4); p5 = fmaf(B1.y, w[40+5], p5);                \
    p6 = fmaf(B1.y, w[40+6], p6); p7 = fmaf(B1.y, w[40+7], p7);                \
    p0 = fmaf(B1.z, w[48+0], p0); p1 = fmaf(B1.z, w[48+1], p1);                \
    p2 = fmaf(B1.z, w[48+2], p2); p3 = fmaf(B1.z, w[48+3], p3);                \
    p4 = fmaf(B1.z, w[48+4], p4); p5 = fmaf(B1.z, w[48+5], p5);                \
    p6 = fmaf(B1.z, w[48+6], p6); p7 = fmaf(B1.z, w[48+7], p7);                \
    p0 = fmaf(B1.w, w[56+0], p0); p1 = fmaf(B1.w, w[56+1], p1);                \
    p2 = fmaf(B1.w, w[56+2], p2); p3 = fmaf(B1.w, w[56+3], p3);                \
    p4 = fmaf(B1.w, w[56+4], p4); p5 = fmaf(B1.w, w[56+5], p5);                \
    p6 = fmaf(B1.w, w[56+6], p6); p7 = fmaf(B1.w, w[56+7], p7);                \
    const bool hi5 = (lane & 32) != 0;   /* head bit 1 */                      \
    float q0 = (hi5 ? p2 : p0) + __shfl_xor(hi5 ? p0 : p2, 32, 64);            \
    float q1 = (hi5 ? p3 : p1) + __shfl_xor(hi5 ? p1 : p3, 32, 64);            \
    float q2 = (hi5 ? p6 : p4) + __shfl_xor(hi5 ? p4 : p6, 32, 64);            \
    float q3 = (hi5 ? p7 : p5) + __shfl_xor(hi5 ? p5 : p7, 32, 64);            \
    const bool hi4 = (lane & 16) != 0;   /* head bit 0 */                      \
    float sA = (hi4 ? q1 : q0) + __shfl_xor(hi4 ? q0 : q1, 16, 64);            \
    float sB = (hi4 ? q3 : q2) + __shfl_xor(hi4 ? q2 : q3, 16, 64);            \
    sA += __shfl_xor(sA, 8, 64);  sB += __shfl_xor(sB, 8, 64);                 \
    sA += __shfl_xor(sA, 4, 64);  sB += __shfl_xor(sB, 4, 64);                 \
    sA += __shfl_xor(sA, 2, 64);  sB += __shfl_xor(sB, 2, 64);                 \
    sA += __shfl_xor(sA, 1, 64);  sB += __shfl_xor(sB, 1, 64);                 \
    const bool valid = (rowmask >> row_) & 1ull;                               \
    const float lgA = valid ? (sA + bsA) * invTA : -1e9f;                      \
    const float lgB = valid ? (sB + bsB) * invTB : -1e9f;                      \
    const bool needA = lgA > mA + 8.0f;                                        \
    const bool needB = lgB > mB + 8.0f;                                        \
    if (__any(needA || needB)) {                                               \
      const float mnA = needA ? lgA : mA;                                      \
      const float scA = __expf(mA - mnA);                                      \
      const float mnB = needB ? lgB : mB;                                      \
      const float scB = __expf(mB - mnB);                                      \
      lA *= scA; lB *= scB;                                                    \
      acc0 *= scA; acc1 *= scA; acc2 *= scA; acc3 *= scA;                      \
      acc4 *= scB; acc5 *= scB; acc6 *= scB; acc7 *= scB;                      \
      mA = mnA; mB = mnB;                                                      \
    }                                                                          \
    const float peA = valid ? __expf(lgA - mA) : 0.0f;                         \
    const float peB = valid ? __expf(lgB - mB) : 0.0f;                         \
    lA += peA; lB += peB;                                                      \
    acc0 = fmaf(peA, B0.x, acc0); acc1 = fmaf(peA, B0.y, acc1);                \
    acc2 = fmaf(peA, B0.z, acc2); acc3 = fmaf(peA, B0.w, acc3);                \
    acc4 = fmaf(peB, B1.x, acc4); acc5 = fmaf(peB, B1.y, acc5);                \
    acc6 = fmaf(peB, B1.z, acc6); acc7 = fmaf(peB, B1.w, acc7);                \
    const int pr_ = (row_ + 2 < ROWS_PER_WAVE) ? (row_ + 2)                    \
                                               : (ROWS_PER_WAVE - 1);          \
    const f4v* pp_ = xb + (size_t)pr_ * (D_DIM / 4);                           \
    B0 = pp_[0];                                                               \
    B1 = pp_[64];                                                              \
  }

// ---------------------------------------------------------------------------
// K1: one block = quarter of a batch row (512 rows, 8 waves, 512 threads,
// 2 blocks/CU, 128-VGPR cap). Streaming online softmax per wave, in-block
// combine of the 8 wave partials via LDS, quarter result to ws. The LAST
// block per b (device-scope atomic counter) runs the full epilogue:
// 4-way merge + gate sigmoid + RMS norm + all three outputs.
// ---------------------------------------------------------------------------
__global__ __launch_bounds__(512, 4) void salience_fused(
    const float* __restrict__ x,
    const void* __restrict__ mask,
    const float* __restrict__ temp,
    const float* __restrict__ w_sal,
    const float* __restrict__ b_sal,
    const float* __restrict__ w_gate,
    const float* __restrict__ b_gate,
    const float* __restrict__ scale,
    int* __restrict__ ws_cnt,
    float* __restrict__ ws_hm,
    float* __restrict__ ws_hl,
    float* __restrict__ ws_hacc,
    float* __restrict__ out)
{
    __shared__ float sm_acc[WAVES][D_DIM];   // 16 KiB
    __shared__ float sm_m[WAVES][H_DIM];
    __shared__ float sm_l[WAVES][H_DIM];
    __shared__ float red[H_DIM];
    __shared__ int   sm_last;

    const int b     = blockIdx.x >> 2;     // CH = 4
    const int chunk = blockIdx.x & 3;
    const int lane  = threadIdx.x & 63;
    const int wv    = threadIdx.x >> 6;    // 0..7
    const int hA    = lane >> 4;           // lane's heads: hA and hA+4

    // Inline mask-format detection (byte-packed vs int32), one ballot.
    const unsigned mv0 = (unsigned)((const int*)mask)[lane];
    const int byte_mask = (__ballot(mv0 > 1u) != 0ull) ? 1 : 0;

    // Register-resident w_sal slice:
    //  w[j*8+hh]     = w_sal[(4*lane+j)*8 + hh]      j=0..3
    //  w[(4+j)*8+hh] = w_sal[(256+4*lane+j)*8 + hh]  j=0..3
    float w[64];
    {
        const float4* wa = (const float4*)(w_sal) + (size_t)lane * 8;
        const float4* wb = (const float4*)(w_sal + 2048) + (size_t)lane * 8;
        #pragma unroll
        for (int q = 0; q < 8; ++q) {
            float4 v = wa[q];
            w[q*4+0] = v.x; w[q*4+1] = v.y; w[q*4+2] = v.z; w[q*4+3] = v.w;
        }
        #pragma unroll
        for (int q = 0; q < 8; ++q) {
            float4 v = wb[q];
            w[32+q*4+0] = v.x; w[32+q*4+1] = v.y; w[32+q*4+2] = v.z; w[32+q*4+3] = v.w;
        }
    }
    const float bsA = b_sal[hA];
    const float bsB = b_sal[hA + 4];
    const float tpA = temp[hA];
    const float tpB = temp[hA + 4];
    const float spA = (tpA > 20.0f) ? tpA : log1pf(__expf(tpA));
    const float spB = (tpB > 20.0f) ? tpB : log1pf(__expf(tpB));
    const float invTA = 1.0f / (spA + 0.3f);
    const float invTB = 1.0f / (spB + 0.3f);

    const int t0 = chunk * ROWS_PER_BLOCK + wv * ROWS_PER_WAVE;
    const size_t mbase = (size_t)b * T_DIM + t0;

    // Mask prefetch: lane r loads row r's mask; one ballot -> 64-bit row mask.
    int mrow = byte_mask ? (int)((const unsigned char*)mask)[mbase + lane]
                         : ((const int*)mask)[mbase + lane];
    const unsigned long long rowmask = __ballot(mrow != 0);

    float mA = -1e9f, lA = 0.0f;
    float mB = -1e9f, lB = 0.0f;
    float acc0 = 0.f, acc1 = 0.f, acc2 = 0.f, acc3 = 0.f;
    float acc4 = 0.f, acc5 = 0.f, acc6 = 0.f, acc7 = 0.f;

    // Dense base: lane i -> f4v index i (bytes 16i) within each 1KB half-row.
    const f4v* xb = (const f4v*)(x + ((size_t)b * T_DIM + t0) * D_DIM) + lane;

    // Prologue: rows 0 and 1 into named buffers (depth-2).
    f4v bA0 = xb[0];
    f4v bA1 = xb[64];
    f4v bB0 = xb[128];
    f4v bB1 = xb[192];

    for (int r2 = 0; r2 < ROWS_PER_WAVE / 2; ++r2) {
        ROW_BODY(2 * r2,     bA0, bA1)
        ROW_BODY(2 * r2 + 1, bB0, bB1)
    }

    // Stash this wave's partials in LDS.
    if ((lane & 15) == 0) {
        sm_m[wv][hA]     = mA;
        sm_m[wv][hA + 4] = mB;
        sm_l[wv][hA]     = lA;
        sm_l[wv][hA + 4] = lB;
    }
    float4* dstA = (float4*)(&sm_acc[wv][0]) + lane;
    dstA[0]  = make_float4(acc0, acc1, acc2, acc3);
    dstA[64] = make_float4(acc4, acc5, acc6, acc7);
    __syncthreads();

    // In-block quarter-combine: all 512 threads, thread = output dim d.
    const int d = threadIdx.x;
    const int h = d >> 6;
    {
        float M = -3.0e38f;
        #pragma unroll
        for (int s = 0; s < WAVES; ++s) M = fmaxf(M, sm_m[s][h]);
        float A = 0.0f, L = 0.0f;
        #pragma unroll
        for (int s = 0; s < WAVES; ++s) {
            const float e = __expf(sm_m[s][h] - M);
            L = fmaf(sm_l[s][h], e, L);
            A = fmaf(sm_acc[s][d], e, A);
        }
        const size_t hc = (size_t)b * CH + chunk;
        ws_hacc[hc * D_DIM + d] = A;
        if ((d & 63) == 0) {
            ws_hm[hc * H_DIM + h] = M;
            ws_hl[hc * H_DIM + h] = L;
        }
    }

    // Elect the last block of this b (device-scope acq_rel; cumulative, so
    // all 4 blocks' quarter-result stores are visible after the final add).
    __syncthreads();
    if (threadIdx.x == 0) {
        const int old = __hip_atomic_fetch_add(&ws_cnt[b], 1, __ATOMIC_ACQ_REL,
                                               __HIP_MEMORY_SCOPE_AGENT);
        sm_last = (old == CH - 1) ? 1 : 0;
    }
    __syncthreads();
    if (!sm_last) return;

    // ---- Epilogue (last block only): 4-way merge + gate + RMS + outputs ----
    const int dd = d & 63;
    const size_t h0 = (size_t)b * CH;
    const float m0 = ws_hm[(h0 + 0) * H_DIM + h];
    const float m1 = ws_hm[(h0 + 1) * H_DIM + h];
    const float m2 = ws_hm[(h0 + 2) * H_DIM + h];
    const float m3 = ws_hm[(h0 + 3) * H_DIM + h];
    const float M  = fmaxf(fmaxf(m0, m1), fmaxf(m2, m3));
    const float e0 = __expf(m0 - M);
    const float e1 = __expf(m1 - M);
    const float e2 = __expf(m2 - M);
    const float e3 = __expf(m3 - M);
    const float L = ws_hl[(h0 + 0) * H_DIM + h] * e0
                  + ws_hl[(h0 + 1) * H_DIM + h] * e1
                  + ws_hl[(h0 + 2) * H_DIM + h] * e2
                  + ws_hl[(h0 + 3) * H_DIM + h] * e3;
    const float A = ws_hacc[(h0 + 0) * D_DIM + d] * e0
                  + ws_hacc[(h0 + 1) * D_DIM + d] * e1
                  + ws_hacc[(h0 + 2) * D_DIM + d] * e2
                  + ws_hacc[(h0 + 3) * D_DIM + d] * e3;
    const float wvv = A / (L + 1e-6f);

    // gate: dot(wv_head, w_gate) within the wave (= head)
    float g = wvv * w_gate[dd];
    #pragma unroll
    for (int s = 1; s < 64; s <<= 1) g += __shfl_xor(g, s, 64);
    const float gl = g + b_gate[0];
    const float u = (L > 0.0f) ? (1.0f / (1.0f + __expf(-gl))) : 0.0f;

    // RMS over the full 512-dim write_vec
    float sq = wvv * wvv;
    #pragma unroll
    for (int s = 1; s < 64; s <<= 1) sq += __shfl_xor(sq, s, 64);
    if (dd == 0) red[h] = sq;
    __syncthreads();
    float ssum = 0.0f;
    #pragma unroll
    for (int k = 0; k < H_DIM; ++k) ssum += red[k];
    const float rms = sqrtf(ssum * (1.0f / (float)D_DIM) + 1e-6f);

    out[(size_t)b * D_DIM + d] = wvv / rms * scale[d];
    out[(size_t)B_DIM * D_DIM + (size_t)b * D_DIM + d] = u;
    if (dd == 0) out[2 * (size_t)B_DIM * D_DIM + (size_t)b * H_DIM + h] = u;
}

// ---------------------------------------------------------------------------
extern "C" void kernel_launch(void* const* d_in, const int* in_sizes, int n_in,
                              void* d_out, int out_size, void* d_ws, size_t ws_size,
                              hipStream_t stream) {
    (void)in_sizes; (void)n_in; (void)out_size; (void)ws_size;
    const float* x      = (const float*)d_in[0];
    const void*  mask   = d_in[1];
    const float* temp   = (const float*)d_in[2];
    const float* w_sal  = (const float*)d_in[3];
    const float* b_sal  = (const float*)d_in[4];
    const float* w_gate = (const float*)d_in[5];
    const float* b_gate = (const float*)d_in[6];
    const float* scale  = (const float*)d_in[7];
    float* out = (float*)d_out;

    char* ws = (char*)d_ws;
    int*   ws_cnt  = (int*)ws;                        // B_DIM ints
    float* ws_hm   = (float*)(ws + 1024);             // CH*B*H floats (16KB)
    float* ws_hl   = (float*)(ws + 1024 + 16384);     // CH*B*H floats (16KB)
    float* ws_hacc = (float*)(ws + 1024 + 32768);     // CH*B*D floats (1MB)

    hipMemsetAsync(ws_cnt, 0, B_DIM * sizeof(int), stream);
    salience_fused<<<B_DIM * CH, WAVES * 64, 0, stream>>>(
        x, mask, temp, w_sal, b_sal, w_gate, b_gate, scale,
        ws_cnt, ws_hm, ws_hl, ws_hacc, out);
}

// Round 10
// 113.164 us; speedup vs baseline: 1.2251x; 1.2251x over previous
//
#include <hip/hip_runtime.h>

// Problem constants
#define B_DIM 128
#define T_DIM 2048
#define D_DIM 512
#define H_DIM 8
#define HD_DIM 64
#define CH 4                          // chunks (blocks) per batch row
#define ROWS_PER_BLOCK (T_DIM / CH)   // 512
#define WAVES 8                       // 512-thread blocks
#define ROWS_PER_WAVE (ROWS_PER_BLOCK / WAVES) // 64 == wave size (ballot)

typedef float f4v __attribute__((ext_vector_type(4)));

// ---------------------------------------------------------------------------
// Per-row body (identical math to round-5 best): 8-head dot partials ->
// reduce-scatter to head pair {hA, hA+4} -> dual-head online softmax with
// deferred max -> depth-2 prefetch reissue.
// ---------------------------------------------------------------------------
#define ROW_BODY(ROW, B0, B1)                                                  \
  {                                                                            \
    const int row_ = (ROW);                                                    \
    float p0 = B0.x * w[0];                                                    \
    float p1 = B0.x * w[1];                                                    \
    float p2 = B0.x * w[2];                                                    \
    float p3 = B0.x * w[3];                                                    \
    float p4 = B0.x * w[4];                                                    \
    float p5 = B0.x * w[5];                                                    \
    float p6 = B0.x * w[6];                                                    \
    float p7 = B0.x * w[7];                                                    \
    p0 = fmaf(B0.y, w[8+0], p0);  p1 = fmaf(B0.y, w[8+1], p1);                 \
    p2 = fmaf(B0.y, w[8+2], p2);  p3 = fmaf(B0.y, w[8+3], p3);                 \
    p4 = fmaf(B0.y, w[8+4], p4);  p5 = fmaf(B0.y, w[8+5], p5);                 \
    p6 = fmaf(B0.y, w[8+6], p6);  p7 = fmaf(B0.y, w[8+7], p7);                 \
    p0 = fmaf(B0.z, w[16+0], p0); p1 = fmaf(B0.z, w[16+1], p1);                \
    p2 = fmaf(B0.z, w[16+2], p2); p3 = fmaf(B0.z, w[16+3], p3);                \
    p4 = fmaf(B0.z, w[16+4], p4); p5 = fmaf(B0.z, w[16+5], p5);                \
    p6 = fmaf(B0.z, w[16+6], p6); p7 = fmaf(B0.z, w[16+7], p7);                \
    p0 = fmaf(B0.w, w[24+0], p0); p1 = fmaf(B0.w, w[24+1], p1);                \
    p2 = fmaf(B0.w, w[24+2], p2); p3 = fmaf(B0.w, w[24+3], p3);                \
    p4 = fmaf(B0.w, w[24+4], p4); p5 = fmaf(B0.w, w[24+5], p5);                \
    p6 = fmaf(B0.w, w[24+6], p6); p7 = fmaf(B0.w, w[24+7], p7);                \
    p0 = fmaf(B1.x, w[32+0], p0); p1 = fmaf(B1.x, w[32+1], p1);                \
    p2 = fmaf(B1.x, w[32+2], p2); p3 = fmaf(B1.x, w[32+3], p3);                \
    p4 = fmaf(B1.x, w[32+4], p4); p5 = fmaf(B1.x, w[32+5], p5);                \
    p6 = fmaf(B1.x, w[32+6], p6); p7 = fmaf(B1.x, w[32+7], p7);                \
    p0 = fmaf(B1.y, w[40+0], p0); p1 = fmaf(B1.y, w[40+1], p1);                \
    p2 = fmaf(B1.y, w[40+2], p2); p3 = fmaf(B1.y, w[40+3], p3);                \
    p4 = fmaf(B1.y, w[40+4], p4); p5 = fmaf(B1.y, w[40+5], p5);                \
    p6 = fmaf(B1.y, w[40+6], p6); p7 = fmaf(B1.y, w[40+7], p7);                \
    p0 = fmaf(B1.z, w[48+0], p0); p1 = fmaf(B1.z, w[48+1], p1);                \
    p2 = fmaf(B1.z, w[48+2], p2); p3 = fmaf(B1.z, w[48+3], p3);                \
    p4 = fmaf(B1.z, w[48+4], p4); p5 = fmaf(B1.z, w[48+5], p5);                \
    p6 = fmaf(B1.z, w[48+6], p6); p7 = fmaf(B1.z, w[48+7], p7);                \
    p0 = fmaf(B1.w, w[56+0], p0); p1 = fmaf(B1.w, w[56+1], p1);                \
    p2 = fmaf(B1.w, w[56+2], p2); p3 = fmaf(B1.w, w[56+3], p3);                \
    p4 = fmaf(B1.w, w[56+4], p4); p5 = fmaf(B1.w, w[56+5], p5);                \
    p6 = fmaf(B1.w, w[56+6], p6); p7 = fmaf(B1.w, w[56+7], p7);                \
    const bool hi5 = (lane & 32) != 0;   /* head bit 1 */                      \
    float q0 = (hi5 ? p2 : p0) + __shfl_xor(hi5 ? p0 : p2, 32, 64);            \
    float q1 = (hi5 ? p3 : p1) + __shfl_xor(hi5 ? p1 : p3, 32, 64);            \
    float q2 = (hi5 ? p6 : p4) + __shfl_xor(hi5 ? p4 : p6, 32, 64);            \
    float q3 = (hi5 ? p7 : p5) + __shfl_xor(hi5 ? p5 : p7, 32, 64);            \
    const bool hi4 = (lane & 16) != 0;   /* head bit 0 */                      \
    float sA = (hi4 ? q1 : q0) + __shfl_xor(hi4 ? q0 : q1, 16, 64);            \
    float sB = (hi4 ? q3 : q2) + __shfl_xor(hi4 ? q2 : q3, 16, 64);            \
    sA += __shfl_xor(sA, 8, 64);  sB += __shfl_xor(sB, 8, 64);                 \
    sA += __shfl_xor(sA, 4, 64);  sB += __shfl_xor(sB, 4, 64);                 \
    sA += __shfl_xor(sA, 2, 64);  sB += __shfl_xor(sB, 2, 64);                 \
    sA += __shfl_xor(sA, 1, 64);  sB += __shfl_xor(sB, 1, 64);                 \
    const bool valid = (rowmask >> row_) & 1ull;                               \
    const float lgA = valid ? (sA + bsA) * invTA : -1e9f;                      \
    const float lgB = valid ? (sB + bsB) * invTB : -1e9f;                      \
    const bool needA = lgA > mA + 8.0f;                                        \
    const bool needB = lgB > mB + 8.0f;                                        \
    if (__any(needA || needB)) {                                               \
      const float mnA = needA ? lgA : mA;                                      \
      const float scA = __expf(mA - mnA);                                      \
      const float mnB = needB ? lgB : mB;                                      \
      const float scB = __expf(mB - mnB);                                      \
      lA *= scA; lB *= scB;                                                    \
      acc0 *= scA; acc1 *= scA; acc2 *= scA; acc3 *= scA;                      \
      acc4 *= scB; acc5 *= scB; acc6 *= scB; acc7 *= scB;                      \
      mA = mnA; mB = mnB;                                                      \
    }                                                                          \
    const float peA = valid ? __expf(lgA - mA) : 0.0f;                         \
    const float peB = valid ? __expf(lgB - mB) : 0.0f;                         \
    lA += peA; lB += peB;                                                      \
    acc0 = fmaf(peA, B0.x, acc0); acc1 = fmaf(peA, B0.y, acc1);                \
    acc2 = fmaf(peA, B0.z, acc2); acc3 = fmaf(peA, B0.w, acc3);                \
    acc4 = fmaf(peB, B1.x, acc4); acc5 = fmaf(peB, B1.y, acc5);                \
    acc6 = fmaf(peB, B1.z, acc6); acc7 = fmaf(peB, B1.w, acc7);                \
    const int pr_ = (row_ + 2 < ROWS_PER_WAVE) ? (row_ + 2)                    \
                                               : (ROWS_PER_WAVE - 1);          \
    const f4v* pp_ = xb + (size_t)pr_ * (D_DIM / 4);                           \
    B0 = pp_[0];                                                               \
    B1 = pp_[64];                                                              \
  }

// ---------------------------------------------------------------------------
// K1: one block = quarter of a batch row (512 rows, 8 waves, 512 threads,
// 2 blocks/CU, 128-VGPR cap -> no spills). Streaming online softmax per wave
// (round-5 body), then in-block combine of the 8 wave partials via LDS.
// Emits one quarter-combined (M, L, A[512]) per (b, chunk).
// ---------------------------------------------------------------------------
__global__ __launch_bounds__(512, 4) void salience_pass1(
    const float* __restrict__ x,
    const void* __restrict__ mask,
    const float* __restrict__ temp,
    const float* __restrict__ w_sal,
    const float* __restrict__ b_sal,
    float* __restrict__ ws_hm,
    float* __restrict__ ws_hl,
    float* __restrict__ ws_hacc)
{
    __shared__ float sm_acc[WAVES][D_DIM];   // 16 KiB
    __shared__ float sm_m[WAVES][H_DIM];
    __shared__ float sm_l[WAVES][H_DIM];

    const int b     = blockIdx.x >> 2;     // CH = 4
    const int chunk = blockIdx.x & 3;
    const int lane  = threadIdx.x & 63;
    const int wv    = threadIdx.x >> 6;    // 0..7
    const int hA    = lane >> 4;           // lane's heads: hA and hA+4

    // Inline mask-format detection (byte-packed vs int32), one ballot.
    const unsigned mv0 = (unsigned)((const int*)mask)[lane];
    const int byte_mask = (__ballot(mv0 > 1u) != 0ull) ? 1 : 0;

    // Register-resident w_sal slice:
    //  w[j*8+hh]     = w_sal[(4*lane+j)*8 + hh]      j=0..3
    //  w[(4+j)*8+hh] = w_sal[(256+4*lane+j)*8 + hh]  j=0..3
    float w[64];
    {
        const float4* wa = (const float4*)(w_sal) + (size_t)lane * 8;
        const float4* wb = (const float4*)(w_sal + 2048) + (size_t)lane * 8;
        #pragma unroll
        for (int q = 0; q < 8; ++q) {
            float4 v = wa[q];
            w[q*4+0] = v.x; w[q*4+1] = v.y; w[q*4+2] = v.z; w[q*4+3] = v.w;
        }
        #pragma unroll
        for (int q = 0; q < 8; ++q) {
            float4 v = wb[q];
            w[32+q*4+0] = v.x; w[32+q*4+1] = v.y; w[32+q*4+2] = v.z; w[32+q*4+3] = v.w;
        }
    }
    const float bsA = b_sal[hA];
    const float bsB = b_sal[hA + 4];
    const float tpA = temp[hA];
    const float tpB = temp[hA + 4];
    const float spA = (tpA > 20.0f) ? tpA : log1pf(__expf(tpA));
    const float spB = (tpB > 20.0f) ? tpB : log1pf(__expf(tpB));
    const float invTA = 1.0f / (spA + 0.3f);
    const float invTB = 1.0f / (spB + 0.3f);

    const int t0 = chunk * ROWS_PER_BLOCK + wv * ROWS_PER_WAVE;
    const size_t mbase = (size_t)b * T_DIM + t0;

    // Mask prefetch: lane r loads row r's mask; one ballot -> 64-bit row mask.
    int mrow = byte_mask ? (int)((const unsigned char*)mask)[mbase + lane]
                         : ((const int*)mask)[mbase + lane];
    const unsigned long long rowmask = __ballot(mrow != 0);

    float mA = -1e9f, lA = 0.0f;
    float mB = -1e9f, lB = 0.0f;
    float acc0 = 0.f, acc1 = 0.f, acc2 = 0.f, acc3 = 0.f;
    float acc4 = 0.f, acc5 = 0.f, acc6 = 0.f, acc7 = 0.f;

    // Dense base: lane i -> f4v index i (bytes 16i) within each 1KB half-row.
    const f4v* xb = (const f4v*)(x + ((size_t)b * T_DIM + t0) * D_DIM) + lane;

    // Prologue: rows 0 and 1 into named buffers (depth-2).
    f4v bA0 = xb[0];
    f4v bA1 = xb[64];
    f4v bB0 = xb[128];
    f4v bB1 = xb[192];

    for (int r2 = 0; r2 < ROWS_PER_WAVE / 2; ++r2) {
        ROW_BODY(2 * r2,     bA0, bA1)
        ROW_BODY(2 * r2 + 1, bB0, bB1)
    }

    // Stash this wave's partials in LDS.
    if ((lane & 15) == 0) {
        sm_m[wv][hA]     = mA;
        sm_m[wv][hA + 4] = mB;
        sm_l[wv][hA]     = lA;
        sm_l[wv][hA + 4] = lB;
    }
    float4* dstA = (float4*)(&sm_acc[wv][0]) + lane;
    dstA[0]  = make_float4(acc0, acc1, acc2, acc3);
    dstA[64] = make_float4(acc4, acc5, acc6, acc7);
    __syncthreads();

    // In-block quarter-combine: all 512 threads, thread = output dim d.
    const int d = threadIdx.x;
    const int h = d >> 6;
    float M = -3.0e38f;
    #pragma unroll
    for (int s = 0; s < WAVES; ++s) M = fmaxf(M, sm_m[s][h]);
    float A = 0.0f, L = 0.0f;
    #pragma unroll
    for (int s = 0; s < WAVES; ++s) {
        const float e = __expf(sm_m[s][h] - M);
        L = fmaf(sm_l[s][h], e, L);
        A = fmaf(sm_acc[s][d], e, A);
    }
    const size_t hc = (size_t)b * CH + chunk;
    ws_hacc[hc * D_DIM + d] = A;
    if ((d & 63) == 0) {
        ws_hm[hc * H_DIM + h] = M;
        ws_hl[hc * H_DIM + h] = L;
    }
}

// ---------------------------------------------------------------------------
// K2': merge the 4 quarter-combines per b, gate sigmoid, RMS norm, store all
// three outputs. One block per b, 512 threads (thread d; wave == head).
// ---------------------------------------------------------------------------
__global__ __launch_bounds__(512) void salience_pass2(
    const float* __restrict__ ws_hm,
    const float* __restrict__ ws_hl,
    const float* __restrict__ ws_hacc,
    const float* __restrict__ w_gate,
    const float* __restrict__ b_gate,
    const float* __restrict__ scale,
    float* __restrict__ out)
{
    const int b  = blockIdx.x;
    const int d  = threadIdx.x;
    const int h  = d >> 6;       // wave == head
    const int dd = d & 63;

    __shared__ float red[H_DIM];

    const size_t h0 = (size_t)b * CH;
    const float m0 = ws_hm[(h0 + 0) * H_DIM + h];
    const float m1 = ws_hm[(h0 + 1) * H_DIM + h];
    const float m2 = ws_hm[(h0 + 2) * H_DIM + h];
    const float m3 = ws_hm[(h0 + 3) * H_DIM + h];
    const float M  = fmaxf(fmaxf(m0, m1), fmaxf(m2, m3));
    const float e0 = __expf(m0 - M);
    const float e1 = __expf(m1 - M);
    const float e2 = __expf(m2 - M);
    const float e3 = __expf(m3 - M);
    const float L = ws_hl[(h0 + 0) * H_DIM + h] * e0
                  + ws_hl[(h0 + 1) * H_DIM + h] * e1
                  + ws_hl[(h0 + 2) * H_DIM + h] * e2
                  + ws_hl[(h0 + 3) * H_DIM + h] * e3;
    const float A = ws_hacc[(h0 + 0) * D_DIM + d] * e0
                  + ws_hacc[(h0 + 1) * D_DIM + d] * e1
                  + ws_hacc[(h0 + 2) * D_DIM + d] * e2
                  + ws_hacc[(h0 + 3) * D_DIM + d] * e3;
    const float wv = A / (L + 1e-6f);

    // gate: dot(wv_head, w_gate) within the wave (= head)
    float g = wv * w_gate[dd];
    #pragma unroll
    for (int s = 1; s < 64; s <<= 1) g += __shfl_xor(g, s, 64);
    const float gl = g + b_gate[0];
    const float u = (L > 0.0f) ? (1.0f / (1.0f + __expf(-gl))) : 0.0f;

    // RMS over the full 512-dim write_vec
    float sq = wv * wv;
    #pragma unroll
    for (int s = 1; s < 64; s <<= 1) sq += __shfl_xor(sq, s, 64);
    if (dd == 0) red[h] = sq;
    __syncthreads();
    float ssum = 0.0f;
    #pragma unroll
    for (int k = 0; k < H_DIM; ++k) ssum += red[k];
    const float rms = sqrtf(ssum * (1.0f / (float)D_DIM) + 1e-6f);

    out[(size_t)b * D_DIM + d] = wv / rms * scale[d];
    out[(size_t)B_DIM * D_DIM + (size_t)b * D_DIM + d] = u;
    if (dd == 0) out[2 * (size_t)B_DIM * D_DIM + (size_t)b * H_DIM + h] = u;
}

// ---------------------------------------------------------------------------
extern "C" void kernel_launch(void* const* d_in, const int* in_sizes, int n_in,
                              void* d_out, int out_size, void* d_ws, size_t ws_size,
                              hipStream_t stream) {
    (void)in_sizes; (void)n_in; (void)out_size; (void)ws_size;
    const float* x      = (const float*)d_in[0];
    const void*  mask   = d_in[1];
    const float* temp   = (const float*)d_in[2];
    const float* w_sal  = (const float*)d_in[3];
    const float* b_sal  = (const float*)d_in[4];
    const float* w_gate = (const float*)d_in[5];
    const float* b_gate = (const float*)d_in[6];
    const float* scale  = (const float*)d_in[7];
    float* out = (float*)d_out;

    char* ws = (char*)d_ws;
    float* ws_hm   = (float*)(ws);                    // 512*8 floats (16KB)
    float* ws_hl   = (float*)(ws + 16384);            // 512*8 floats (16KB)
    float* ws_hacc = (float*)(ws + 32768);            // 512*512 floats (1MB)

    salience_pass1<<<B_DIM * CH, WAVES * 64, 0, stream>>>(
        x, mask, temp, w_sal, b_sal, ws_hm, ws_hl, ws_hacc);
    salience_pass2<<<B_DIM, 512, 0, stream>>>(
        ws_hm, ws_hl, ws_hacc, w_gate, b_gate, scale, out);
}